// Round 2
// baseline (438.717 us; speedup 1.0000x reference)
//
#include <hip/hip_runtime.h>
#include <float.h>

#define NB 16
#define NH 16
#define SS 577
#define DD 1024
#define NSEL 257           // NUM_COUNT + 1
#define TOPK 64            // per-head candidate list length (>= worst realistic need)
#define PH 16              // picks per head = NUM_COUNT / H

#define HIDDEN_ELEMS (NB * SS * DD)     // 9,453,568 floats
#define HIDDEN_V4 (HIDDEN_ELEMS / 4)    // 2,363,392 float4
#define SEL_ELEMS (NB * NSEL * DD)      // 4,210,688 floats
#define SEL_V4 (SEL_ELEMS / 4)          // 1,052,672 float4

__device__ __forceinline__ void pair_max_reduce(float& bv, int& bi) {
    // max by (value desc, index asc) across 64 lanes; result in all lanes
    #pragma unroll
    for (int off = 1; off < 64; off <<= 1) {
        float ov = __shfl_xor(bv, off, 64);
        int   oi = __shfl_xor(bi, off, 64);
        if (ov > bv || (ov == bv && oi < bi)) { bv = ov; bi = oi; }
    }
}

// K1: blocks [0, 256): per-(b,h) top-64 sorted candidate indices (wave 0 only).
//     blocks [256, ...): grid-stride float4 copy hidden -> out[0:HIDDEN].
__global__ __launch_bounds__(256)
void k_topk_copy(const float* __restrict__ hidden,
                 const float* __restrict__ attn,
                 float* __restrict__ out,
                 int* __restrict__ cand) {
    int blk = blockIdx.x;
    if (blk < NB * NH) {
        if (threadIdx.x >= 64) return;   // no barriers on this path
        int lane = threadIdx.x;
        // CLS row: attention[b][h][0][:]
        const float* row = attn + (size_t)blk * ((size_t)SS * SS);
        float v[9];
        #pragma unroll
        for (int s = 0; s < 9; ++s) v[s] = row[1 + lane + 64 * s];  // idx 1..576

        float bv; int bi;
        // local best over this lane's 9 values (tie -> smaller s = smaller idx)
        bv = -FLT_MAX; bi = 0x7fffffff;
        #pragma unroll
        for (int s = 0; s < 9; ++s)
            if (v[s] > bv) { bv = v[s]; bi = 1 + lane + 64 * s; }

        int mine = 0;
        for (int t = 0; t < TOPK; ++t) {
            float wv = bv; int wi = bi;
            pair_max_reduce(wv, wi);
            if (lane == t) mine = wi;                // lane t records rank-t winner
            int wl = (wi - 1) & 63;                  // owner lane of winner
            if (lane == wl) {
                int wslot = (wi - 1) >> 6;
                #pragma unroll
                for (int s = 0; s < 9; ++s) if (s == wslot) v[s] = -FLT_MAX;
                bv = -FLT_MAX; bi = 0x7fffffff;
                #pragma unroll
                for (int s = 0; s < 9; ++s)
                    if (v[s] > bv) { bv = v[s]; bi = 1 + lane + 64 * s; }
            }
        }
        cand[blk * TOPK + lane] = mine;              // coalesced store, sorted by rank
    } else {
        const float4* src = (const float4*)hidden;
        float4* dst = (float4*)out;
        size_t stride = (size_t)(gridDim.x - NB * NH) * blockDim.x;
        for (size_t i = (size_t)(blk - NB * NH) * blockDim.x + threadIdx.x;
             i < (size_t)HIDDEN_V4; i += stride)
            dst[i] = src[i];
    }
}

// K2: per-batch sequential merge over heads (reference set-union semantics).
__global__ __launch_bounds__(64)
void k_merge(const float* __restrict__ attn,
             const int* __restrict__ cand,
             int* __restrict__ sel) {
    int b = blockIdx.x;
    int lane = threadIdx.x;
    __shared__ unsigned char member[SS];
    for (int i = lane; i < SS; i += 64) member[i] = 0;
    if (lane == 0) member[0] = 1;
    __builtin_amdgcn_wave_barrier();

    unsigned long long lowmask = (lane == 0) ? 0ull : ((1ull << lane) - 1ull);

    for (int h = 0; h < NH; ++h) {
        int c = cand[(b * NH + h) * TOPK + lane];    // rank-`lane` candidate
        int avail = member[c] ? 0 : 1;
        unsigned long long bal = __ballot(avail);
        int rank = __popcll(bal & lowmask);
        if (avail && rank < PH) member[c] = 1;       // take first 16 new, in rank order
        int got = __popcll(bal);
        if (got < PH) {
            // Rare fallback: fewer than 16 new in top-64 -> exact argmax continuation.
            int need = (got > PH ? 0 : PH - got);
            const float* row = attn + (size_t)(b * NH + h) * ((size_t)SS * SS);
            float v[9];
            #pragma unroll
            for (int s = 0; s < 9; ++s) {
                int idx = 1 + lane + 64 * s;
                v[s] = member[idx] ? -FLT_MAX : row[idx];
            }
            for (int t = 0; t < need; ++t) {
                float bv = -FLT_MAX; int bi = 0x7fffffff;
                #pragma unroll
                for (int s = 0; s < 9; ++s)
                    if (v[s] > bv) { bv = v[s]; bi = 1 + lane + 64 * s; }
                pair_max_reduce(bv, bi);
                int wl = (bi - 1) & 63;
                if (lane == wl) {
                    int wslot = (bi - 1) >> 6;
                    #pragma unroll
                    for (int s = 0; s < 9; ++s) if (s == wslot) v[s] = -FLT_MAX;
                    member[bi] = 1;
                }
                __builtin_amdgcn_wave_barrier();
            }
        }
        __builtin_amdgcn_wave_barrier();
    }

    // Emit sorted member list (257 indices, ascending) via chunked ballot prefix.
    int pos = 0;
    #pragma unroll
    for (int s = 0; s < 10; ++s) {
        int i = s * 64 + lane;
        int m = (i < SS) ? (member[i] ? 1 : 0) : 0;
        unsigned long long bal = __ballot(m);
        int rank = __popcll(bal & lowmask);
        if (m) sel[b * NSEL + pos + rank] = i;
        pos += __popcll(bal);
    }
}

// K3: gather selected rows -> out[HIDDEN:]
__global__ __launch_bounds__(256)
void k_gather(const float* __restrict__ hidden,
              const int* __restrict__ sel,
              float* __restrict__ out) {
    const float4* src = (const float4*)hidden;
    float4* dst = (float4*)(out + (size_t)HIDDEN_ELEMS);
    size_t stride = (size_t)gridDim.x * blockDim.x;
    for (size_t i = (size_t)blockIdx.x * blockDim.x + threadIdx.x;
         i < (size_t)SEL_V4; i += stride) {
        size_t rowi = i >> 8;                 // 256 float4 per D=1024 row
        int d4 = (int)(i & 255);
        int b = (int)(rowi / NSEL);
        int j = (int)(rowi - (size_t)b * NSEL);
        int r = sel[b * NSEL + j];            // wave-uniform-ish scalar load
        dst[i] = src[(((size_t)(b * SS + r)) << 8) + d4];
    }
}

extern "C" void kernel_launch(void* const* d_in, const int* in_sizes, int n_in,
                              void* d_out, int out_size, void* d_ws, size_t ws_size,
                              hipStream_t stream) {
    const float* hidden = (const float*)d_in[0];  // [16,577,1024] f32
    const float* attn   = (const float*)d_in[1];  // [16,16,577,577] f32
    float* out = (float*)d_out;                   // [hidden | selected] f32
    int* cand = (int*)d_ws;                       // [256][64] int
    int* sel  = cand + NB * NH * TOPK;            // [16][257] int

    k_topk_copy<<<NB * NH + 1792, 256, 0, stream>>>(hidden, attn, out, cand);
    k_merge<<<NB, 64, 0, stream>>>(attn, cand, sel);
    k_gather<<<1024, 256, 0, stream>>>(hidden, sel, out);
}